// Round 7
// baseline (41.590 us; speedup 1.0000x reference)
//
#include <hip/hip_runtime.h>
#include <hip/hip_bf16.h>

// Problem constants (B=4, T=4096, C=2048, E=64)
#define N_TOK   16384
#define C_DIM   2048
#define E_DIM   64
#define P_OFF   (N_TOK * E_DIM)        // 1048576 — end of probs section
#define FB_OFF  P_OFF                  // fallback_count scalar
#define LG_OFF  (P_OFF + 1)            // logits section
#define AM_OFF  (2 * P_OFF + 1)        // activation_mask section

#define BPK_BYTES  262144              // 256 KB prepacked B
#define PART_BYTES ((size_t)4 * N_TOK * E_DIM * 4)   // 16.8 MB partials

typedef __attribute__((ext_vector_type(8))) short bf16x8;  // 8 bf16 in 4 VGPRs
typedef __attribute__((ext_vector_type(4))) float f32x4;

static __device__ __forceinline__ unsigned short f2bf_rtn(float f) {
    unsigned u = __float_as_uint(f);
    unsigned r = u + 0x7FFFu + ((u >> 16) & 1u);   // round-to-nearest-even
    return (unsigned short)(r >> 16);
}

// ---------------------------------------------------------------------------
// Kernel 1: prepack sim_matrix [2048,64] f32 -> bf16 (RTN) MFMA fragments.
// kk-step it (32 k): layout [it(64)][nb(4)][lane(64)][i(8)] shorts (256 KB).
// Content: lane l, elem i -> sim[it*32 + (l>>4)*8 + i][nb*16 + (l&15)]
// Also zero-initializes the fallback counter in d_out.
// ---------------------------------------------------------------------------
__global__ void gating_prepack(const float* __restrict__ sim,
                               unsigned short* __restrict__ Bpk,
                               float* __restrict__ out) {
    int tid = blockIdx.x * 256 + threadIdx.x;
    if (tid == 0) out[FB_OFF] = 0.0f;
    if (tid >= C_DIM * E_DIM) return;
    int k = tid >> 6;
    int e = tid & 63;
    float v = sim[tid];                       // sim[k*64 + e]
    int it = k >> 5;                          // kk-step 0..63
    int gr = (k >> 3) & 3;
    int i  = k & 7;
    int lane = gr * 16 + (e & 15);
    int nb   = e >> 4;
    Bpk[it * 2048 + nb * 512 + lane * 8 + i] = f2bf_rtn(v);
}

// ---------------------------------------------------------------------------
// Phase 1: split-K GEMM. Grid 512 x 512 threads (8 waves; 2 blocks/CU,
// 16 waves/CU). Block (kq = bid&3, tg = bid>>2): tokens tg*128..+127,
// K-range kq*512..+511. The 64 KB B-quarter is staged ONCE into LDS
// (global_load_lds, linear layout = prepack order), one barrier; then the
// K-loop has A as the ONLY vmcnt stream (chunk-dbuf prefetch is clean) and
// B on lgkmcnt via conflict-free ds_read_b128. Writes f32 partials:
// part[kq][t][e0(16)][nb(4)]  (float4 per lane).
// ---------------------------------------------------------------------------
__global__ __launch_bounds__(512, 4)
void gating_gemm(const float* __restrict__ x,
                 const unsigned short* __restrict__ Bpk,
                 float* __restrict__ part) {
    __shared__ unsigned short Blds[32768];   // 64 KB: B quarter

    const int tid = threadIdx.x;
    const int kq  = blockIdx.x & 3;
    const int tg  = blockIdx.x >> 2;

    // ---- stage B quarter: 512 thr x 8 x 16 B, linear ----
    const unsigned short* bq = Bpk + kq * 32768;
#pragma unroll
    for (int j = 0; j < 8; ++j) {
        __builtin_amdgcn_global_load_lds(
            (const __attribute__((address_space(1))) unsigned int*)(bq + j * 4096 + tid * 8),
            (__attribute__((address_space(3))) unsigned int*)(&Blds[j * 4096 + tid * 8]),
            16, 0, 0);
    }
    __syncthreads();

    const int l   = tid & 63;
    const int w   = tid >> 6;          // wave id 0..7 -> 16-token group
    const int g   = l >> 4;
    const int e0  = l & 15;
    const int trow0 = tg * 128 + w * 16;
    const float* xr = x + (size_t)(trow0 + e0) * C_DIM + kq * 512 + g * 8;

    f32x4 acc[4];
#pragma unroll
    for (int nb = 0; nb < 4; ++nb) acc[nb] = (f32x4)0.0f;

    // A chunk double-buffer: 2 kk-steps per chunk
    float4 Ac[2][2][2];
#pragma unroll
    for (int st = 0; st < 2; ++st) {
        const float* ap = xr + st * 32;
        Ac[0][st][0] = *(const float4*)ap;
        Ac[0][st][1] = *(const float4*)(ap + 4);
    }

#pragma unroll
    for (int c = 0; c < 8; ++c) {
        const int cur = c & 1, nxt = cur ^ 1;
        if (c < 7) {
#pragma unroll
            for (int st = 0; st < 2; ++st) {
                const float* ap = xr + ((c + 1) * 2 + st) * 32;
                Ac[nxt][st][0] = *(const float4*)ap;
                Ac[nxt][st][1] = *(const float4*)(ap + 4);
            }
        }
#pragma unroll
        for (int st = 0; st < 2; ++st) {
            const int it = c * 2 + st;
            float av[8] = {Ac[cur][st][0].x, Ac[cur][st][0].y,
                           Ac[cur][st][0].z, Ac[cur][st][0].w,
                           Ac[cur][st][1].x, Ac[cur][st][1].y,
                           Ac[cur][st][1].z, Ac[cur][st][1].w};
            bf16x8 ah;
#pragma unroll
            for (int i = 0; i < 8; ++i) ah[i] = (short)f2bf_rtn(av[i]);
#pragma unroll
            for (int nb = 0; nb < 4; ++nb) {
                bf16x8 bf = *(const bf16x8*)(&Blds[it * 2048 + nb * 512 + l * 8]);
                acc[nb] = __builtin_amdgcn_mfma_f32_16x16x32_bf16(ah, bf, acc[nb], 0, 0, 0);
            }
        }
    }

    // ---- store partials: float4 per (token, e0) ----
    float4* pp = (float4*)part;
#pragma unroll
    for (int r = 0; r < 4; ++r) {
        int t = trow0 + g * 4 + r;               // C/D row = (l>>4)*4 + reg
        float4 v = {acc[0][r], acc[1][r], acc[2][r], acc[3][r]};
        pp[(size_t)(kq * N_TOK + t) * 16 + e0] = v;
    }
}

// ---------------------------------------------------------------------------
// Phase 2: reduce 4 K-partials + gating epilogue.
// Grid 256 x 256 (4 waves). Block: 64 tokens; wave w: 16 tokens.
// Lane (g,e0) handles tokens t = blk*64 + w*16 + g*4 + r, experts nb*16+e0.
// ---------------------------------------------------------------------------
__global__ __launch_bounds__(256, 4)
void gating_epi(const float* __restrict__ part,
                const float* __restrict__ gates,
                float* __restrict__ out) {
    const int tid = threadIdx.x;
    const int l   = tid & 63;
    const int w   = tid >> 6;
    const int g   = l >> 4;
    const int e0  = l & 15;
    const float4* pp = (const float4*)part;

    float sig[4];
#pragma unroll
    for (int nb = 0; nb < 4; ++nb)
        sig[nb] = 1.0f / (1.0f + expf(-gates[nb * 16 + e0]));

#pragma unroll
    for (int r = 0; r < 4; ++r) {
        const int t = blockIdx.x * 64 + w * 16 + g * 4 + r;
        float4 tot = pp[(size_t)(0 * N_TOK + t) * 16 + e0];
#pragma unroll
        for (int s = 1; s < 4; ++s) {
            float4 v = pp[(size_t)(s * N_TOK + t) * 16 + e0];
            tot.x += v.x; tot.y += v.y; tot.z += v.z; tot.w += v.w;
        }
        float lg[4] = {tot.x - sig[0], tot.y - sig[1], tot.z - sig[2], tot.w - sig[3]};
        bool  act[4];
        int   lcnt = 0;
        float lmax = -3.4e38f;
#pragma unroll
        for (int nb = 0; nb < 4; ++nb) {
            act[nb] = lg[nb] > 0.0f;
            if (act[nb]) { lcnt++; lmax = fmaxf(lmax, lg[nb]); }
        }
        int cnt = lcnt;
        float mx = lmax;
#pragma unroll
        for (int m = 1; m < 16; m <<= 1) {
            cnt += __shfl_xor(cnt, m, 16);
            mx   = fmaxf(mx, __shfl_xor(mx, m, 16));
        }

        float p[4], am[4];
        if (cnt > 0) {
            float ex[4], ls = 0.0f;
#pragma unroll
            for (int nb = 0; nb < 4; ++nb) {
                ex[nb] = act[nb] ? expf(lg[nb] - mx) : 0.0f;
                ls += ex[nb];
            }
            float Z = ls;
#pragma unroll
            for (int m = 1; m < 16; m <<= 1) Z += __shfl_xor(Z, m, 16);
            float rz = 1.0f / Z;
#pragma unroll
            for (int nb = 0; nb < 4; ++nb) {
                p[nb]  = ex[nb] * rz;
                am[nb] = act[nb] ? 1.0f : 0.0f;
            }
        } else {
            // fallback: top-32 of 64 logits (ties -> lower expert index);
            // all logits <= 0 here, so probs are uniform 1/32 over the set.
            unsigned selm = 0;
            for (int it = 0; it < 32; ++it) {
                float bv = -3.4e38f;
                int   bi = 127;
#pragma unroll
                for (int nb = 0; nb < 4; ++nb) {
                    if (!((selm >> nb) & 1)) {
                        float v = lg[nb];
                        int   e = nb * 16 + e0;
                        if (v > bv || (v == bv && e < bi)) { bv = v; bi = e; }
                    }
                }
#pragma unroll
                for (int m = 1; m < 16; m <<= 1) {
                    float ov = __shfl_xor(bv, m, 16);
                    int   oi = __shfl_xor(bi, m, 16);
                    if (ov > bv || (ov == bv && oi < bi)) { bv = ov; bi = oi; }
                }
                if ((bi & 15) == e0) selm |= 1u << (bi >> 4);
            }
#pragma unroll
            for (int nb = 0; nb < 4; ++nb) {
                bool s_ = (selm >> nb) & 1;
                p[nb]  = s_ ? (1.0f / 32.0f) : 0.0f;
                am[nb] = s_ ? 1.0f : 0.0f;
            }
            if (e0 == 0) atomicAdd(&out[FB_OFF], 1.0f);
        }

#pragma unroll
        for (int nb = 0; nb < 4; ++nb) {
            int idx = t * 64 + nb * 16 + e0;
            out[idx]          = p[nb];
            out[LG_OFF + idx] = lg[nb];
            out[AM_OFF + idx] = am[nb];
        }
    }
}

// ---------------------------------------------------------------------------
// Fallback mono kernel (R5 structure) if ws_size can't hold the partials.
// ---------------------------------------------------------------------------
__global__ __launch_bounds__(256, 4)
void gating_mono(const float* __restrict__ x,
                 const unsigned short* __restrict__ Bpk,
                 const float* __restrict__ gates,
                 float* __restrict__ out) {
    __shared__ float red[4][16][64];

    const int tid = threadIdx.x;
    const int l   = tid & 63;
    const int w   = tid >> 6;
    const int row0 = blockIdx.x * 16;
    const int g    = l >> 4;
    const int e0   = l & 15;
    const float* xr = x + (size_t)(row0 + e0) * C_DIM + w * 512 + g * 8;
    const unsigned short* bw = Bpk + (size_t)w * 16 * 2048 + l * 8;

    f32x4 acc[4];
#pragma unroll
    for (int nb = 0; nb < 4; ++nb) acc[nb] = (f32x4)0.0f;

    bf16x8 Bf[2][4];
#pragma unroll
    for (int b = 0; b < 2; ++b)
#pragma unroll
        for (int f = 0; f < 4; ++f)
            Bf[b][f] = *(const bf16x8*)(bw + b * 2048 + f * 512);
    float4 Ar[4][2];
#pragma unroll
    for (int it = 0; it < 4; ++it) {
        const float* ap = xr + it * 32;
        Ar[it][0] = *(const float4*)ap;
        Ar[it][1] = *(const float4*)(ap + 4);
    }

#pragma unroll
    for (int it = 0; it < 16; ++it) {
        const int sl = it & 3;
        const int bb = it & 1;
        bf16x8 bnx[4];
        if (it < 14) {
            const unsigned short* bp = bw + (it + 2) * 2048;
#pragma unroll
            for (int f = 0; f < 4; ++f) bnx[f] = *(const bf16x8*)(bp + f * 512);
        }
        float av[8] = {Ar[sl][0].x, Ar[sl][0].y, Ar[sl][0].z, Ar[sl][0].w,
                       Ar[sl][1].x, Ar[sl][1].y, Ar[sl][1].z, Ar[sl][1].w};
        if (it < 12) {
            const float* ap = xr + (it + 4) * 32;
            Ar[sl][0] = *(const float4*)ap;
            Ar[sl][1] = *(const float4*)(ap + 4);
        }
        bf16x8 ah;
#pragma unroll
        for (int i = 0; i < 8; ++i) ah[i] = (short)f2bf_rtn(av[i]);
#pragma unroll
        for (int nb = 0; nb < 4; ++nb)
            acc[nb] = __builtin_amdgcn_mfma_f32_16x16x32_bf16(ah, Bf[bb][nb], acc[nb], 0, 0, 0);
        if (it < 14) {
#pragma unroll
            for (int f = 0; f < 4; ++f) Bf[bb][f] = bnx[f];
        }
    }

#pragma unroll
    for (int nb = 0; nb < 4; ++nb)
#pragma unroll
        for (int r = 0; r < 4; ++r)
            red[w][nb * 4 + r][l] = acc[nb][r];
    __syncthreads();

    float tot[4];
#pragma unroll
    for (int nb = 0; nb < 4; ++nb)
        tot[nb] = red[0][nb * 4 + w][l] + red[1][nb * 4 + w][l]
                + red[2][nb * 4 + w][l] + red[3][nb * 4 + w][l];

    float sig[4];
#pragma unroll
    for (int nb = 0; nb < 4; ++nb)
        sig[nb] = 1.0f / (1.0f + expf(-gates[nb * 16 + e0]));

    const int t = row0 + g * 4 + w;
    float lg[4];
    bool  act[4];
    int   lcnt = 0;
    float lmax = -3.4e38f;
#pragma unroll
    for (int nb = 0; nb < 4; ++nb) {
        lg[nb]  = tot[nb] - sig[nb];
        act[nb] = lg[nb] > 0.0f;
        if (act[nb]) { lcnt++; lmax = fmaxf(lmax, lg[nb]); }
    }
    int cnt = lcnt;
    float mx = lmax;
#pragma unroll
    for (int m = 1; m < 16; m <<= 1) {
        cnt += __shfl_xor(cnt, m, 16);
        mx   = fmaxf(mx, __shfl_xor(mx, m, 16));
    }

    float p[4], am[4];
    if (cnt > 0) {
        float ex[4], ls = 0.0f;
#pragma unroll
        for (int nb = 0; nb < 4; ++nb) {
            ex[nb] = act[nb] ? expf(lg[nb] - mx) : 0.0f;
            ls += ex[nb];
        }
        float Z = ls;
#pragma unroll
        for (int m = 1; m < 16; m <<= 1) Z += __shfl_xor(Z, m, 16);
        float rz = 1.0f / Z;
#pragma unroll
        for (int nb = 0; nb < 4; ++nb) {
            p[nb]  = ex[nb] * rz;
            am[nb] = act[nb] ? 1.0f : 0.0f;
        }
    } else {
        unsigned selm = 0;
        for (int it = 0; it < 32; ++it) {
            float bv = -3.4e38f;
            int   bi = 127;
#pragma unroll
            for (int nb = 0; nb < 4; ++nb) {
                if (!((selm >> nb) & 1)) {
                    float v = lg[nb];
                    int   e = nb * 16 + e0;
                    if (v > bv || (v == bv && e < bi)) { bv = v; bi = e; }
                }
            }
#pragma unroll
            for (int m = 1; m < 16; m <<= 1) {
                float ov = __shfl_xor(bv, m, 16);
                int   oi = __shfl_xor(bi, m, 16);
                if (ov > bv || (ov == bv && oi < bi)) { bv = ov; bi = oi; }
            }
            if ((bi & 15) == e0) selm |= 1u << (bi >> 4);
        }
#pragma unroll
        for (int nb = 0; nb < 4; ++nb) {
            bool s_ = (selm >> nb) & 1;
            p[nb]  = s_ ? (1.0f / 32.0f) : 0.0f;
            am[nb] = s_ ? 1.0f : 0.0f;
        }
        if (e0 == 0) atomicAdd(&out[FB_OFF], 1.0f);
    }

#pragma unroll
    for (int nb = 0; nb < 4; ++nb) {
        int idx = t * 64 + nb * 16 + e0;
        out[idx]          = p[nb];
        out[LG_OFF + idx] = lg[nb];
        out[AM_OFF + idx] = am[nb];
    }
}

// ---------------------------------------------------------------------------
extern "C" void kernel_launch(void* const* d_in, const int* in_sizes, int n_in,
                              void* d_out, int out_size, void* d_ws, size_t ws_size,
                              hipStream_t stream) {
    const float* x     = (const float*)d_in[0];   // [4,4096,2048] f32
    const float* sim   = (const float*)d_in[1];   // [2048,64] f32
    const float* gates = (const float*)d_in[2];   // [64] f32
    float* out = (float*)d_out;
    unsigned short* Bpk = (unsigned short*)d_ws;  // 256 KB prepacked B (bf16)

    gating_prepack<<<512, 256, 0, stream>>>(sim, Bpk, out);

    if (ws_size >= BPK_BYTES + PART_BYTES) {
        float* part = (float*)((char*)d_ws + BPK_BYTES);
        gating_gemm<<<512, 512, 0, stream>>>(x, Bpk, part);
        gating_epi<<<256, 256, 0, stream>>>(part, gates, out);
    } else {
        gating_mono<<<1024, 256, 0, stream>>>(x, Bpk, gates, out);
    }
}

// Round 8
// 40.534 us; speedup vs baseline: 1.0261x; 1.0261x over previous
//
#include <hip/hip_runtime.h>
#include <hip/hip_bf16.h>

// Problem constants (B=4, T=4096, C=2048, E=64)
#define N_TOK   16384
#define C_DIM   2048
#define E_DIM   64
#define P_OFF   (N_TOK * E_DIM)        // 1048576 — end of probs section
#define FB_OFF  P_OFF                  // fallback_count scalar
#define LG_OFF  (P_OFF + 1)            // logits section
#define AM_OFF  (2 * P_OFF + 1)        // activation_mask section

#define BPK_BYTES  262144              // 256 KB prepacked B
#define PART_BYTES ((size_t)4 * N_TOK * E_DIM * 2)   // 8.4 MB bf16 partials

typedef __attribute__((ext_vector_type(8))) short bf16x8;  // 8 bf16 in 4 VGPRs
typedef __attribute__((ext_vector_type(4))) float f32x4;

static __device__ __forceinline__ unsigned short f2bf_rtn(float f) {
    unsigned u = __float_as_uint(f);
    unsigned r = u + 0x7FFFu + ((u >> 16) & 1u);   // round-to-nearest-even
    return (unsigned short)(r >> 16);
}
static __device__ __forceinline__ float bf2f(unsigned short h) {
    return __uint_as_float(((unsigned)h) << 16);
}

// ---------------------------------------------------------------------------
// Kernel 1: prepack sim_matrix [2048,64] f32 -> bf16 (RTN) MFMA fragments.
// kk-step it (32 k): layout [it(64)][nb(4)][lane(64)][i(8)] shorts (256 KB).
// Content: lane l, elem i -> sim[it*32 + (l>>4)*8 + i][nb*16 + (l&15)]
// Also zero-initializes the fallback counter in d_out.
// ---------------------------------------------------------------------------
__global__ void gating_prepack(const float* __restrict__ sim,
                               unsigned short* __restrict__ Bpk,
                               float* __restrict__ out) {
    int tid = blockIdx.x * 256 + threadIdx.x;
    if (tid == 0) out[FB_OFF] = 0.0f;
    if (tid >= C_DIM * E_DIM) return;
    int k = tid >> 6;
    int e = tid & 63;
    float v = sim[tid];                       // sim[k*64 + e]
    int it = k >> 5;                          // kk-step 0..63
    int gr = (k >> 3) & 3;
    int i  = k & 7;
    int lane = gr * 16 + (e & 15);
    int nb   = e >> 4;
    Bpk[it * 2048 + nb * 512 + lane * 8 + i] = f2bf_rtn(v);
}

// ---------------------------------------------------------------------------
// Phase 1: split-K GEMM. Grid 512 x 512 thr (8 waves; 64 KB LDS -> 2 blk/CU,
// 16 waves/CU). Block (kq = bid&3, tg = bid>>2): tokens tg*128..+127,
// K-range kq*512..+511 (16 kk-steps). B-quarter staged ONCE into LDS
// (global_load_lds, linear prepack order) -> B lives on lgkmcnt only.
// A is then the SOLE vmcnt stream: ring of 4 chunks x 2 kk-steps gives
// 8-step (~1000cy) prefetch distance; the wait at chunk c drains exactly
// chunk c (c+1..c+3 issued after, stay in flight). Writes bf16 partials:
// part[kq][t][e0(16)][nb(4)]  (ushort4 per lane).
// ---------------------------------------------------------------------------
__global__ __launch_bounds__(512, 4)
void gating_gemm(const float* __restrict__ x,
                 const unsigned short* __restrict__ Bpk,
                 unsigned short* __restrict__ part) {
    __shared__ unsigned short Blds[32768];   // 64 KB: B quarter

    const int tid = threadIdx.x;
    const int kq  = blockIdx.x & 3;
    const int tg  = blockIdx.x >> 2;

    // ---- stage B quarter: 512 thr x 8 x 16 B, linear ----
    const unsigned short* bq = Bpk + kq * 32768;
#pragma unroll
    for (int j = 0; j < 8; ++j) {
        __builtin_amdgcn_global_load_lds(
            (const __attribute__((address_space(1))) unsigned int*)(bq + j * 4096 + tid * 8),
            (__attribute__((address_space(3))) unsigned int*)(&Blds[j * 4096 + tid * 8]),
            16, 0, 0);
    }
    __syncthreads();

    const int l   = tid & 63;
    const int w   = tid >> 6;          // wave id 0..7 -> 16-token group
    const int g   = l >> 4;
    const int e0  = l & 15;
    const int trow0 = tg * 128 + w * 16;
    const float* xr = x + (size_t)(trow0 + e0) * C_DIM + kq * 512 + g * 8;

    f32x4 acc[4];
#pragma unroll
    for (int nb = 0; nb < 4; ++nb) acc[nb] = (f32x4)0.0f;

    // ---- A ring: 4 chunks x 2 kk-steps x 2 float4 = 64 VGPR ----
    float4 Ac[4][2][2];
#pragma unroll
    for (int c = 0; c < 4; ++c)
#pragma unroll
        for (int st = 0; st < 2; ++st) {
            const float* ap = xr + (c * 2 + st) * 32;
            Ac[c][st][0] = *(const float4*)ap;
            Ac[c][st][1] = *(const float4*)(ap + 4);
        }

    // ---- 8 chunks of 2 kk-steps, fully unrolled ----
#pragma unroll
    for (int c = 0; c < 8; ++c) {
        const int sl = c & 3;

        // extract chunk c (first use -> waits exactly on chunk c's loads)
        float av[2][8];
#pragma unroll
        for (int st = 0; st < 2; ++st) {
            av[st][0] = Ac[sl][st][0].x; av[st][1] = Ac[sl][st][0].y;
            av[st][2] = Ac[sl][st][0].z; av[st][3] = Ac[sl][st][0].w;
            av[st][4] = Ac[sl][st][1].x; av[st][5] = Ac[sl][st][1].y;
            av[st][6] = Ac[sl][st][1].z; av[st][7] = Ac[sl][st][1].w;
        }

        // refill slot with chunk c+4 (8 kk-steps ahead)
        if (c < 4) {
#pragma unroll
            for (int st = 0; st < 2; ++st) {
                const float* ap = xr + ((c + 4) * 2 + st) * 32;
                Ac[sl][st][0] = *(const float4*)ap;
                Ac[sl][st][1] = *(const float4*)(ap + 4);
            }
        }

        // compute chunk c: pack + 4 MFMA per step (B via ds_read_b128)
#pragma unroll
        for (int st = 0; st < 2; ++st) {
            const int it = c * 2 + st;
            bf16x8 ah;
#pragma unroll
            for (int i = 0; i < 8; ++i) ah[i] = (short)f2bf_rtn(av[st][i]);
#pragma unroll
            for (int nb = 0; nb < 4; ++nb) {
                bf16x8 bf = *(const bf16x8*)(&Blds[it * 2048 + nb * 512 + l * 8]);
                acc[nb] = __builtin_amdgcn_mfma_f32_16x16x32_bf16(ah, bf, acc[nb], 0, 0, 0);
            }
        }
    }

    // ---- store bf16 partials: ushort4 per (token, e0) ----
    ushort4* pp = (ushort4*)part;
#pragma unroll
    for (int r = 0; r < 4; ++r) {
        int t = trow0 + g * 4 + r;               // C/D row = (l>>4)*4 + reg
        ushort4 v;
        v.x = f2bf_rtn(acc[0][r]); v.y = f2bf_rtn(acc[1][r]);
        v.z = f2bf_rtn(acc[2][r]); v.w = f2bf_rtn(acc[3][r]);
        pp[(size_t)(kq * N_TOK + t) * 16 + e0] = v;
    }
}

// ---------------------------------------------------------------------------
// Phase 2: reduce 4 bf16 K-partials + gating epilogue.
// Grid 256 x 256 (4 waves). Block: 64 tokens; wave w: 16 tokens.
// Lane (g,e0) handles tokens t = blk*64 + w*16 + g*4 + r, experts nb*16+e0.
// ---------------------------------------------------------------------------
__global__ __launch_bounds__(256, 4)
void gating_epi(const unsigned short* __restrict__ part,
                const float* __restrict__ gates,
                float* __restrict__ out) {
    const int tid = threadIdx.x;
    const int l   = tid & 63;
    const int w   = tid >> 6;
    const int g   = l >> 4;
    const int e0  = l & 15;
    const ushort4* pp = (const ushort4*)part;

    float sig[4];
#pragma unroll
    for (int nb = 0; nb < 4; ++nb)
        sig[nb] = 1.0f / (1.0f + expf(-gates[nb * 16 + e0]));

#pragma unroll
    for (int r = 0; r < 4; ++r) {
        const int t = blockIdx.x * 64 + w * 16 + g * 4 + r;
        float tot[4] = {0.0f, 0.0f, 0.0f, 0.0f};
#pragma unroll
        for (int s = 0; s < 4; ++s) {
            ushort4 v = pp[(size_t)(s * N_TOK + t) * 16 + e0];
            tot[0] += bf2f(v.x); tot[1] += bf2f(v.y);
            tot[2] += bf2f(v.z); tot[3] += bf2f(v.w);
        }
        float lg[4] = {tot[0] - sig[0], tot[1] - sig[1],
                       tot[2] - sig[2], tot[3] - sig[3]};
        bool  act[4];
        int   lcnt = 0;
        float lmax = -3.4e38f;
#pragma unroll
        for (int nb = 0; nb < 4; ++nb) {
            act[nb] = lg[nb] > 0.0f;
            if (act[nb]) { lcnt++; lmax = fmaxf(lmax, lg[nb]); }
        }
        int cnt = lcnt;
        float mx = lmax;
#pragma unroll
        for (int m = 1; m < 16; m <<= 1) {
            cnt += __shfl_xor(cnt, m, 16);
            mx   = fmaxf(mx, __shfl_xor(mx, m, 16));
        }

        float p[4], am[4];
        if (cnt > 0) {
            float ex[4], ls = 0.0f;
#pragma unroll
            for (int nb = 0; nb < 4; ++nb) {
                ex[nb] = act[nb] ? expf(lg[nb] - mx) : 0.0f;
                ls += ex[nb];
            }
            float Z = ls;
#pragma unroll
            for (int m = 1; m < 16; m <<= 1) Z += __shfl_xor(Z, m, 16);
            float rz = 1.0f / Z;
#pragma unroll
            for (int nb = 0; nb < 4; ++nb) {
                p[nb]  = ex[nb] * rz;
                am[nb] = act[nb] ? 1.0f : 0.0f;
            }
        } else {
            // fallback: top-32 of 64 logits (ties -> lower expert index);
            // all logits <= 0 here, so probs are uniform 1/32 over the set.
            unsigned selm = 0;
            for (int it = 0; it < 32; ++it) {
                float bv = -3.4e38f;
                int   bi = 127;
#pragma unroll
                for (int nb = 0; nb < 4; ++nb) {
                    if (!((selm >> nb) & 1)) {
                        float v = lg[nb];
                        int   e = nb * 16 + e0;
                        if (v > bv || (v == bv && e < bi)) { bv = v; bi = e; }
                    }
                }
#pragma unroll
                for (int m = 1; m < 16; m <<= 1) {
                    float ov = __shfl_xor(bv, m, 16);
                    int   oi = __shfl_xor(bi, m, 16);
                    if (ov > bv || (ov == bv && oi < bi)) { bv = ov; bi = oi; }
                }
                if ((bi & 15) == e0) selm |= 1u << (bi >> 4);
            }
#pragma unroll
            for (int nb = 0; nb < 4; ++nb) {
                bool s_ = (selm >> nb) & 1;
                p[nb]  = s_ ? (1.0f / 32.0f) : 0.0f;
                am[nb] = s_ ? 1.0f : 0.0f;
            }
            if (e0 == 0) atomicAdd(&out[FB_OFF], 1.0f);
        }

#pragma unroll
        for (int nb = 0; nb < 4; ++nb) {
            int idx = t * 64 + nb * 16 + e0;
            out[idx]          = p[nb];
            out[LG_OFF + idx] = lg[nb];
            out[AM_OFF + idx] = am[nb];
        }
    }
}

// ---------------------------------------------------------------------------
// Fallback mono kernel (R5 structure) if ws_size can't hold the partials.
// ---------------------------------------------------------------------------
__global__ __launch_bounds__(256, 4)
void gating_mono(const float* __restrict__ x,
                 const unsigned short* __restrict__ Bpk,
                 const float* __restrict__ gates,
                 float* __restrict__ out) {
    __shared__ float red[4][16][64];

    const int tid = threadIdx.x;
    const int l   = tid & 63;
    const int w   = tid >> 6;
    const int row0 = blockIdx.x * 16;
    const int g    = l >> 4;
    const int e0   = l & 15;
    const float* xr = x + (size_t)(row0 + e0) * C_DIM + w * 512 + g * 8;
    const unsigned short* bw = Bpk + (size_t)w * 16 * 2048 + l * 8;

    f32x4 acc[4];
#pragma unroll
    for (int nb = 0; nb < 4; ++nb) acc[nb] = (f32x4)0.0f;

    bf16x8 Bf[2][4];
#pragma unroll
    for (int b = 0; b < 2; ++b)
#pragma unroll
        for (int f = 0; f < 4; ++f)
            Bf[b][f] = *(const bf16x8*)(bw + b * 2048 + f * 512);
    float4 Ar[4][2];
#pragma unroll
    for (int it = 0; it < 4; ++it) {
        const float* ap = xr + it * 32;
        Ar[it][0] = *(const float4*)ap;
        Ar[it][1] = *(const float4*)(ap + 4);
    }

#pragma unroll
    for (int it = 0; it < 16; ++it) {
        const int sl = it & 3;
        const int bb = it & 1;
        bf16x8 bnx[4];
        if (it < 14) {
            const unsigned short* bp = bw + (it + 2) * 2048;
#pragma unroll
            for (int f = 0; f < 4; ++f) bnx[f] = *(const bf16x8*)(bp + f * 512);
        }
        float av[8] = {Ar[sl][0].x, Ar[sl][0].y, Ar[sl][0].z, Ar[sl][0].w,
                       Ar[sl][1].x, Ar[sl][1].y, Ar[sl][1].z, Ar[sl][1].w};
        if (it < 12) {
            const float* ap = xr + (it + 4) * 32;
            Ar[sl][0] = *(const float4*)ap;
            Ar[sl][1] = *(const float4*)(ap + 4);
        }
        bf16x8 ah;
#pragma unroll
        for (int i = 0; i < 8; ++i) ah[i] = (short)f2bf_rtn(av[i]);
#pragma unroll
        for (int nb = 0; nb < 4; ++nb)
            acc[nb] = __builtin_amdgcn_mfma_f32_16x16x32_bf16(ah, Bf[bb][nb], acc[nb], 0, 0, 0);
        if (it < 14) {
#pragma unroll
            for (int f = 0; f < 4; ++f) Bf[bb][f] = bnx[f];
        }
    }

#pragma unroll
    for (int nb = 0; nb < 4; ++nb)
#pragma unroll
        for (int r = 0; r < 4; ++r)
            red[w][nb * 4 + r][l] = acc[nb][r];
    __syncthreads();

    float tot[4];
#pragma unroll
    for (int nb = 0; nb < 4; ++nb)
        tot[nb] = red[0][nb * 4 + w][l] + red[1][nb * 4 + w][l]
                + red[2][nb * 4 + w][l] + red[3][nb * 4 + w][l];

    float sig[4];
#pragma unroll
    for (int nb = 0; nb < 4; ++nb)
        sig[nb] = 1.0f / (1.0f + expf(-gates[nb * 16 + e0]));

    const int t = row0 + g * 4 + w;
    float lg[4];
    bool  act[4];
    int   lcnt = 0;
    float lmax = -3.4e38f;
#pragma unroll
    for (int nb = 0; nb < 4; ++nb) {
        lg[nb]  = tot[nb] - sig[nb];
        act[nb] = lg[nb] > 0.0f;
        if (act[nb]) { lcnt++; lmax = fmaxf(lmax, lg[nb]); }
    }
    int cnt = lcnt;
    float mx = lmax;
#pragma unroll
    for (int m = 1; m < 16; m <<= 1) {
        cnt += __shfl_xor(cnt, m, 16);
        mx   = fmaxf(mx, __shfl_xor(mx, m, 16));
    }

    float p[4], am[4];
    if (cnt > 0) {
        float ex[4], ls = 0.0f;
#pragma unroll
        for (int nb = 0; nb < 4; ++nb) {
            ex[nb] = act[nb] ? expf(lg[nb] - mx) : 0.0f;
            ls += ex[nb];
        }
        float Z = ls;
#pragma unroll
        for (int m = 1; m < 16; m <<= 1) Z += __shfl_xor(Z, m, 16);
        float rz = 1.0f / Z;
#pragma unroll
        for (int nb = 0; nb < 4; ++nb) {
            p[nb]  = ex[nb] * rz;
            am[nb] = act[nb] ? 1.0f : 0.0f;
        }
    } else {
        unsigned selm = 0;
        for (int it = 0; it < 32; ++it) {
            float bv = -3.4e38f;
            int   bi = 127;
#pragma unroll
            for (int nb = 0; nb < 4; ++nb) {
                if (!((selm >> nb) & 1)) {
                    float v = lg[nb];
                    int   e = nb * 16 + e0;
                    if (v > bv || (v == bv && e < bi)) { bv = v; bi = e; }
                }
            }
#pragma unroll
            for (int m = 1; m < 16; m <<= 1) {
                float ov = __shfl_xor(bv, m, 16);
                int   oi = __shfl_xor(bi, m, 16);
                if (ov > bv || (ov == bv && oi < bi)) { bv = ov; bi = oi; }
            }
            if ((bi & 15) == e0) selm |= 1u << (bi >> 4);
        }
#pragma unroll
        for (int nb = 0; nb < 4; ++nb) {
            bool s_ = (selm >> nb) & 1;
            p[nb]  = s_ ? (1.0f / 32.0f) : 0.0f;
            am[nb] = s_ ? 1.0f : 0.0f;
        }
        if (e0 == 0) atomicAdd(&out[FB_OFF], 1.0f);
    }

#pragma unroll
    for (int nb = 0; nb < 4; ++nb) {
        int idx = t * 64 + nb * 16 + e0;
        out[idx]          = p[nb];
        out[LG_OFF + idx] = lg[nb];
        out[AM_OFF + idx] = am[nb];
    }
}

// ---------------------------------------------------------------------------
extern "C" void kernel_launch(void* const* d_in, const int* in_sizes, int n_in,
                              void* d_out, int out_size, void* d_ws, size_t ws_size,
                              hipStream_t stream) {
    const float* x     = (const float*)d_in[0];   // [4,4096,2048] f32
    const float* sim   = (const float*)d_in[1];   // [2048,64] f32
    const float* gates = (const float*)d_in[2];   // [64] f32
    float* out = (float*)d_out;
    unsigned short* Bpk = (unsigned short*)d_ws;  // 256 KB prepacked B (bf16)

    gating_prepack<<<512, 256, 0, stream>>>(sim, Bpk, out);

    if (ws_size >= BPK_BYTES + PART_BYTES) {
        unsigned short* part = (unsigned short*)((char*)d_ws + BPK_BYTES);
        gating_gemm<<<512, 512, 0, stream>>>(x, Bpk, part);
        gating_epi<<<256, 256, 0, stream>>>(part, gates, out);
    } else {
        gating_mono<<<1024, 256, 0, stream>>>(x, Bpk, gates, out);
    }
}